// Round 5
// baseline (226.654 us; speedup 1.0000x reference)
//
#include <hip/hip_runtime.h>
#include <hip/hip_bf16.h>
#include <cstdint>

#define B_ 2
#define C_ 128
#define E_ 60000

typedef unsigned int uint32_;
typedef unsigned short ushort_;
typedef float v2f __attribute__((ext_vector_type(2)));
typedef float v4f __attribute__((ext_vector_type(4)));

// unpack 4 bf16 from a uint2 (channel order: x.lo, x.hi, y.lo, y.hi)
__device__ __forceinline__ v4f bp4(uint2 v) {
    v4f r;
    r.x = __uint_as_float(v.x << 16);
    r.y = __uint_as_float(v.x & 0xffff0000u);
    r.z = __uint_as_float(v.y << 16);
    r.w = __uint_as_float(v.y & 0xffff0000u);
    return r;
}

__device__ __forceinline__ v4f vabs4(v4f a) {
    v4f r; r.x = fabsf(a.x); r.y = fabsf(a.y); r.z = fabsf(a.z); r.w = fabsf(a.w);
    return r;
}

// float -> bf16 round-to-nearest-even
__device__ __forceinline__ ushort_ f2b(float f) {
    union { float f; uint32_ u; } x; x.f = f;
    uint32_ u = x.u + 0x7fffu + ((x.u >> 16) & 1u);
    return (ushort_)(u >> 16);
}

// within-32-lane-group xor-add via ds_swizzle (and_mask 0x1F keeps halves separate)
__device__ __forceinline__ float swz_add(float v, const int pat) {
    switch (pat) {
    case 1:  return v + __int_as_float(__builtin_amdgcn_ds_swizzle(__float_as_int(v), 0x041F));
    case 2:  return v + __int_as_float(__builtin_amdgcn_ds_swizzle(__float_as_int(v), 0x081F));
    case 4:  return v + __int_as_float(__builtin_amdgcn_ds_swizzle(__float_as_int(v), 0x101F));
    case 8:  return v + __int_as_float(__builtin_amdgcn_ds_swizzle(__float_as_int(v), 0x201F));
    default: return v + __int_as_float(__builtin_amdgcn_ds_swizzle(__float_as_int(v), 0x401F));
    }
}

// ---------------------------------------------------------------------------
// Kernel A: fold (own launch again -- prep now needs Vw for the y0 self
// projection, so same-launch merge would race). 4-wave o-split, chain=16.
// Blocks 0..59: Vw fold. Block 60: cst.
// ---------------------------------------------------------------------------
__global__ __launch_bounds__(256) void fold_kernel(
    const float* __restrict__ Wa_local, const float* __restrict__ ba_local,
    const float* __restrict__ Wb_local, const float* __restrict__ bb_local,
    const float* __restrict__ Wa_tri,  const float* __restrict__ ba_tri,
    const float* __restrict__ Wb_tri,  const float* __restrict__ bb_tri,
    const float* __restrict__ Wa_fuse, const float* __restrict__ ba_fuse,
    const float* __restrict__ Wb_fuse, const float* __restrict__ bb_fuse,
    float* __restrict__ Vw, float* __restrict__ cst)
{
    __shared__ float smem[256];
    const int lane = threadIdx.x & 63;
    const int wv   = threadIdx.x >> 6;

    if (blockIdx.x < 60) {
        const int pj    = blockIdx.x / 10;   // 0..5  (p,j)
        const int chunk = blockIdx.x % 10;   // 0..9
        const int p = pj / 3, j = pj % 3;
        const int f = chunk * 64 + lane;     // flat c*5+s
        const float* Wf = p ? Wb_fuse : Wa_fuse;   // [3][256]
        const float* Wt = p ? Wb_tri  : Wa_tri;    // [128][128][5] flat o*640+f
        const float* Wl = p ? Wb_local : Wa_local; // [128][128]
        const int o0 = wv * 32;              // each wave owns 32 of 128 o's
        float a0 = 0.f, a1 = 0.f, a2 = 0.f, a3 = 0.f;
        for (int o = o0; o < o0 + 32; o += 4) {
            a0 += Wf[j * 256 + 128 + o]     * Wt[(o)     * 640 + f];
            a1 += Wf[j * 256 + 129 + o]     * Wt[(o + 1) * 640 + f];
            a2 += Wf[j * 256 + 130 + o]     * Wt[(o + 2) * 640 + f];
            a3 += Wf[j * 256 + 131 + o]     * Wt[(o + 3) * 640 + f];
        }
        float acc = (a0 + a1) + (a2 + a3);
        const int s = f % 5, c = f / 5;
        if (s == 0) {   // absorb local conv into s=0 slot
            float b0 = 0.f, b1 = 0.f, b2 = 0.f, b3 = 0.f;
            for (int o = o0; o < o0 + 32; o += 4) {
                b0 += Wf[j * 256 + o]     * Wl[(o)     * C_ + c];
                b1 += Wf[j * 256 + o + 1] * Wl[(o + 1) * C_ + c];
                b2 += Wf[j * 256 + o + 2] * Wl[(o + 2) * C_ + c];
                b3 += Wf[j * 256 + o + 3] * Wl[(o + 3) * C_ + c];
            }
            acc += (b0 + b1) + (b2 + b3);
        }
        smem[wv * 64 + lane] = acc;
        __syncthreads();
        if (wv == 0) {
            float tot = smem[lane] + smem[64 + lane] + smem[128 + lane] + smem[192 + lane];
            Vw[(pj * 5 + s) * C_ + c] = tot;
        }
    } else {
        const int j = wv;
        if (j < 3) {
            float acc;
            {
                const int l = lane;
                acc = Wa_fuse[j * 256 + l]       * ba_local[l]
                    + Wa_fuse[j * 256 + 128 + l] * ba_tri[l]
                    + Wb_fuse[j * 256 + l]       * bb_local[l]
                    + Wb_fuse[j * 256 + 128 + l] * bb_tri[l];
            }
            {
                const int l = lane + 64;
                acc += Wa_fuse[j * 256 + l]       * ba_local[l]
                     + Wa_fuse[j * 256 + 128 + l] * ba_tri[l]
                     + Wb_fuse[j * 256 + l]       * bb_local[l]
                     + Wb_fuse[j * 256 + 128 + l] * bb_tri[l];
            }
            acc = swz_add(acc, 1); acc = swz_add(acc, 2); acc = swz_add(acc, 4);
            acc = swz_add(acc, 8); acc = swz_add(acc, 16);
            acc += __shfl_xor(acc, 32, 64);
            if (lane == 0) cst[j] = acc + ba_fuse[j] + bb_fuse[j];
        }
    }
}

// LDS tile addressing: [e][row] with row = p*128+c (record order).
// Row-stride 264 ushorts (16 B aligned rows of 8-ushort groups).
// XOR-swizzle group index with (e>>3)&7 to break bank aliasing on the
// strided ds_write_u16 phase while keeping 8-ushort groups b128-readable.
__device__ __forceinline__ int lds_off(int e, int row) {
    return e * 264 + (((row >> 3) ^ ((e >> 3) & 7)) << 3) + (row & 7);
}

// ---------------------------------------------------------------------------
// Kernel B: transpose+quantize with FULL-RECORD tiles + y0 self projection.
// Tile = 64 e x 256 rows (both tensors, all channels):
//   reads:  256 B contiguous per (p,c) row (vs 128 B before)
//   writes: full 512 B records, 1 KB contiguous per wave-instruction
//   y0_j[e] = sum_{p,c} Vw[p,j,0,c]*x_bf16[p,c,e]  (3 f32/edge) so mesh can
//   skip the 61 MB self-record stream entirely.
// LDS 34.8 KB -> 4 blocks/CU. 16 independent loads/thread (MLP).
// ---------------------------------------------------------------------------
__global__ __launch_bounds__(256) void prep_kernel(
    const float* __restrict__ x0, const float* __restrict__ x1,
    const float* __restrict__ Vw,
    ushort_* __restrict__ xt, float* __restrict__ y0)
{
    __shared__ __align__(16) ushort_ tile[64 * 264];
    __shared__ float wsm[768];               // Vw s=0 slice: [p][j][c]
    const int t = threadIdx.x;
    const int l = t & 63;
    const int w = t >> 6;
    const int b  = blockIdx.y;
    const int e0 = blockIdx.x * 64;
    const int nvalid = min(64, E_ - e0);     // 64, or 32 on the tail tile

    for (int f = t; f < 768; f += 256) {     // 3 weights/thread
        const int p = f / 384, rem = f - p * 384;
        const int j = rem >> 7, c = rem & 127;
        wsm[f] = Vw[((p * 3 + j) * 5) * C_ + c];
    }

    // ---- read + quantize: 16 rounds, 16-lane-contiguous 256 B chunks ----
    const int rowi = t >> 4;                 // 0..15
    const int e4   = (t & 15) * 4;
    const bool rdok = e4 < nvalid;
#pragma unroll
    for (int r = 0; r < 16; ++r) {
        const int row = r * 16 + rowi;       // 0..255 = p*128+c
        const int p = row >> 7, c = row & 127;
        if (rdok) {
            const float* src = (p ? x1 : x0) + ((size_t)b * C_ + c) * E_ + e0 + e4;
            float4 v = *(const float4*)src;
            tile[lds_off(e4 + 0, row)] = f2b(v.x);
            tile[lds_off(e4 + 1, row)] = f2b(v.y);
            tile[lds_off(e4 + 2, row)] = f2b(v.z);
            tile[lds_off(e4 + 3, row)] = f2b(v.w);
        }
    }
    __syncthreads();

    // ---- record write-out: per instr k, wave stores 1 KB contiguous ----
#pragma unroll
    for (int k = 0; k < 8; ++k) {
        const int rec = w * 16 + k * 2 + (l >> 5);   // edge within tile
        const int g   = l & 31;                      // 8-ushort group in record
        const uint4 vv = *(const uint4*)(tile + rec * 264 + ((g ^ ((rec >> 3) & 7)) << 3));
        if (rec < nvalid)
            *(uint4*)(xt + ((size_t)(b * E_ + e0 + rec) << 8) + g * 8) = vv;
    }

    // ---- y0 projection: thread (e = t>>2, q = t&3) owns 64 rows ----
    {
        const int e = t >> 2, q = t & 3;
        const int p = q >> 1;
        const int xr = (e >> 3) & 7;
        float a0 = 0.f, a1 = 0.f, a2 = 0.f;
        const float* w0 = wsm + p * 384;
        const float* w1 = w0 + 128;
        const float* w2 = w1 + 128;
#pragma unroll
        for (int i = 0; i < 8; ++i) {
            const int grp = q * 8 + i;
            const uint4 u = *(const uint4*)(tile + e * 264 + ((grp ^ xr) << 3));
            const int cb = (q & 1) * 64 + i * 8;
            const uint32_ uu[4] = {u.x, u.y, u.z, u.w};
#pragma unroll
            for (int m = 0; m < 4; ++m) {
                const float flo = __uint_as_float(uu[m] << 16);
                const float fhi = __uint_as_float(uu[m] & 0xffff0000u);
                const int c = cb + 2 * m;
                a0 += w0[c] * flo + w0[c + 1] * fhi;
                a1 += w1[c] * flo + w1[c + 1] * fhi;
                a2 += w2[c] * flo + w2[c + 1] * fhi;
            }
        }
        a0 = swz_add(a0, 1); a1 = swz_add(a1, 1); a2 = swz_add(a2, 1);
        a0 = swz_add(a0, 2); a1 = swz_add(a1, 2); a2 = swz_add(a2, 2);
        if (q == 0 && e < nvalid) {
            const size_t eb = (size_t)b * 3 * E_ + e0 + e;   // [b][j][E]
            y0[eb]          = a0;
            y0[eb + E_]     = a1;
            y0[eb + 2 * E_] = a2;
        }
    }
}

// ---------------------------------------------------------------------------
// Kernel C: gather + features + projection, SELF-STREAM REMOVED.
// Per pair: 8 random record gathers (neighbors only) + one float2 y0 read.
// Logical random traffic 246 MB (was 307 incl. self). Weights only s=1..4.
// ---------------------------------------------------------------------------
__global__ __launch_bounds__(256, 4) void mesh_kernel(
    const uint2* __restrict__ xt2, const int* __restrict__ gemm,
    const float* __restrict__ Vw, const float* __restrict__ cst,
    const float* __restrict__ y0, float* __restrict__ out)
{
    const int lane = threadIdx.x & 63;
    const int wv   = threadIdx.x >> 6;
    const int gw   = blockIdx.x * 4 + wv;
    const int nw   = gridDim.x * 4;

    const int p  = lane >> 5;          // tensor this lane handles
    const int c4 = (lane & 31) * 4;    // first of 4 channels this lane handles
    v4f w[3][4];                       // s = 1..4 only (self folded into y0)
#pragma unroll
    for (int j = 0; j < 3; ++j)
#pragma unroll
        for (int s = 1; s < 5; ++s)
            w[j][s - 1] = *(const v4f*)(Vw + ((p * 3 + j) * 5 + s) * C_ + c4);

    const int  jj     = lane >> 4;                 // 0..3
    const int  jjc    = jj < 3 ? jj : 2;
    const bool is0    = (jj == 0), is1 = (jj == 1);
    const bool writer = ((lane & 15) == 0) && (jj < 3);
    const float cj    = is0 ? cst[0] : (is1 ? cst[1] : cst[2]);
    float* obase      = out + (size_t)jjc * E_;

    const int4* g4 = (const int4*)gemm;
    const int npair = (B_ * E_) / 2;               // gw < npair (nw <= 8192)

    int4 giA = g4[2 * gw], giB = g4[2 * gw + 1];   // index prefetch

    for (int pair = gw; pair < npair; pair += nw) {
        const int nxt = pair + nw;
        const int4 gA = giA, gB = giB;
        if (nxt < npair) { giA = g4[2 * nxt]; giB = g4[2 * nxt + 1]; }

        const int e0 = 2 * pair;                   // global edge id of edge A
        const int bb = (e0 >= E_) ? 1 : 0;
        const uint32_ badd = bb ? (uint32_)E_ : 0u;
        const int ee = e0 - (int)badd;

        // 8 wave-wide 512 B gathers (uint2 per lane), all independent
        const uint2 A1 = xt2[((badd + (uint32_)gA.x) << 6) + lane];
        const uint2 A2 = xt2[((badd + (uint32_)gA.y) << 6) + lane];
        const uint2 A3 = xt2[((badd + (uint32_)gA.z) << 6) + lane];
        const uint2 A4 = xt2[((badd + (uint32_)gA.w) << 6) + lane];
        const uint2 B1 = xt2[((badd + (uint32_)gB.x) << 6) + lane];
        const uint2 B2 = xt2[((badd + (uint32_)gB.y) << 6) + lane];
        const uint2 B3 = xt2[((badd + (uint32_)gB.z) << 6) + lane];
        const uint2 B4 = xt2[((badd + (uint32_)gB.w) << 6) + lane];
        // self projection for both edges (sequential, 8 B)
        const float2 yj = *(const float2*)(y0 + ((size_t)bb * 3 + jjc) * E_ + ee);

        // ---- edge A ----
        float rA0, rA1, rA2;
        {
            v4f a1 = bp4(A1), a2 = bp4(A2), a3 = bp4(A3), a4 = bp4(A4);
            v4f s1 = a1 + a3, s2 = a2 + a4;
            v4f d1 = vabs4(a1 - a3), d2 = vabs4(a2 - a4);
            v4f t0 = w[0][0] * s1, t1 = w[1][0] * s1, t2 = w[2][0] * s1;
            t0 += w[0][1] * s2; t1 += w[1][1] * s2; t2 += w[2][1] * s2;
            t0 += w[0][2] * d1; t1 += w[1][2] * d1; t2 += w[2][2] * d1;
            t0 += w[0][3] * d2; t1 += w[1][3] * d2; t2 += w[2][3] * d2;
            rA0 = (t0.x + t0.y) + (t0.z + t0.w);
            rA1 = (t1.x + t1.y) + (t1.z + t1.w);
            rA2 = (t2.x + t2.y) + (t2.z + t2.w);
        }
        // ---- edge B ----
        float rB0, rB1, rB2;
        {
            v4f a1 = bp4(B1), a2 = bp4(B2), a3 = bp4(B3), a4 = bp4(B4);
            v4f s1 = a1 + a3, s2 = a2 + a4;
            v4f d1 = vabs4(a1 - a3), d2 = vabs4(a2 - a4);
            v4f t0 = w[0][0] * s1, t1 = w[1][0] * s1, t2 = w[2][0] * s1;
            t0 += w[0][1] * s2; t1 += w[1][1] * s2; t2 += w[2][1] * s2;
            t0 += w[0][2] * d1; t1 += w[1][2] * d1; t2 += w[2][2] * d1;
            t0 += w[0][3] * d2; t1 += w[1][3] * d2; t2 += w[2][3] * d2;
            rB0 = (t0.x + t0.y) + (t0.z + t0.w);
            rB1 = (t1.x + t1.y) + (t1.z + t1.w);
            rB2 = (t2.x + t2.y) + (t2.z + t2.w);
        }

        // full 64-lane reduce, A/B chains interleaved
        rA0 = swz_add(rA0, 16); rB0 = swz_add(rB0, 16);
        rA1 = swz_add(rA1, 16); rB1 = swz_add(rB1, 16);
        rA2 = swz_add(rA2, 16); rB2 = swz_add(rB2, 16);
        rA0 += __shfl_xor(rA0, 32, 64); rB0 += __shfl_xor(rB0, 32, 64);
        rA1 += __shfl_xor(rA1, 32, 64); rB1 += __shfl_xor(rB1, 32, 64);
        rA2 += __shfl_xor(rA2, 32, 64); rB2 += __shfl_xor(rB2, 32, 64);

        float vA = is0 ? rA0 : (is1 ? rA1 : rA2);
        float vB = is0 ? rB0 : (is1 ? rB1 : rB2);
        vA = swz_add(vA, 1); vB = swz_add(vB, 1);
        vA = swz_add(vA, 2); vB = swz_add(vB, 2);
        vA = swz_add(vA, 4); vB = swz_add(vB, 4);
        vA = swz_add(vA, 8); vB = swz_add(vB, 8);

        if (writer) {
            float2 st; st.x = vA + yj.x + cj; st.y = vB + yj.y + cj;
            *(float2*)(obase + (bb ? 3 * E_ : 0) + ee) = st;   // ee even -> aligned
        }
    }
}

extern "C" void kernel_launch(void* const* d_in, const int* in_sizes, int n_in,
                              void* d_out, int out_size, void* d_ws, size_t ws_size,
                              hipStream_t stream) {
    const float* x0       = (const float*)d_in[0];
    const float* x1       = (const float*)d_in[1];
    const int*   gemm     = (const int*)d_in[2];
    const float* Wa_local = (const float*)d_in[3];
    const float* ba_local = (const float*)d_in[4];
    const float* Wb_local = (const float*)d_in[5];
    const float* bb_local = (const float*)d_in[6];
    const float* Wa_tri   = (const float*)d_in[7];
    const float* ba_tri   = (const float*)d_in[8];
    const float* Wb_tri   = (const float*)d_in[9];
    const float* bb_tri   = (const float*)d_in[10];
    const float* Wa_fuse  = (const float*)d_in[11];
    const float* ba_fuse  = (const float*)d_in[12];
    const float* Wb_fuse  = (const float*)d_in[13];
    const float* bb_fuse  = (const float*)d_in[14];
    float* out = (float*)d_out;

    ushort_* xt  = (ushort_*)d_ws;                        // [B][E][2][C] bf16
    float*   y0  = (float*)(xt + (size_t)B_ * E_ * 2 * C_);  // [B][3][E] f32
    float*   Vw  = y0 + (size_t)B_ * 3 * E_;
    float*   cst = Vw + 2 * 3 * 5 * C_;

    hipLaunchKernelGGL(fold_kernel, dim3(61), dim3(256), 0, stream,
                       Wa_local, ba_local, Wb_local, bb_local,
                       Wa_tri, ba_tri, Wb_tri, bb_tri,
                       Wa_fuse, ba_fuse, Wb_fuse, bb_fuse, Vw, cst);

    hipLaunchKernelGGL(prep_kernel, dim3((E_ + 63) / 64, B_), dim3(256), 0, stream,
                       x0, x1, Vw, xt, y0);

    hipLaunchKernelGGL(mesh_kernel, dim3(2048), dim3(256), 0, stream,
                       (const uint2*)xt, gemm, Vw, cst, y0, out);
}

// Round 6
// 214.173 us; speedup vs baseline: 1.0583x; 1.0583x over previous
//
#include <hip/hip_runtime.h>
#include <hip/hip_bf16.h>
#include <cstdint>

#define B_ 2
#define C_ 128
#define E_ 60000

typedef unsigned int uint32_;
typedef unsigned short ushort_;
typedef float v4f __attribute__((ext_vector_type(4)));

// unpack 4 bf16 from a uint2 (channel order: x.lo, x.hi, y.lo, y.hi)
__device__ __forceinline__ v4f bp4(uint2 v) {
    v4f r;
    r.x = __uint_as_float(v.x << 16);
    r.y = __uint_as_float(v.x & 0xffff0000u);
    r.z = __uint_as_float(v.y << 16);
    r.w = __uint_as_float(v.y & 0xffff0000u);
    return r;
}

__device__ __forceinline__ v4f vabs4(v4f a) {
    v4f r; r.x = fabsf(a.x); r.y = fabsf(a.y); r.z = fabsf(a.z); r.w = fabsf(a.w);
    return r;
}

// float -> bf16 round-to-nearest-even
__device__ __forceinline__ ushort_ f2b(float f) {
    union { float f; uint32_ u; } x; x.f = f;
    uint32_ u = x.u + 0x7fffu + ((x.u >> 16) & 1u);
    return (ushort_)(u >> 16);
}

// within-32-lane-group xor-add via ds_swizzle (and_mask 0x1F keeps halves separate)
__device__ __forceinline__ float swz_add(float v, const int pat) {
    switch (pat) {
    case 1:  return v + __int_as_float(__builtin_amdgcn_ds_swizzle(__float_as_int(v), 0x041F));
    case 2:  return v + __int_as_float(__builtin_amdgcn_ds_swizzle(__float_as_int(v), 0x081F));
    case 4:  return v + __int_as_float(__builtin_amdgcn_ds_swizzle(__float_as_int(v), 0x101F));
    case 8:  return v + __int_as_float(__builtin_amdgcn_ds_swizzle(__float_as_int(v), 0x201F));
    default: return v + __int_as_float(__builtin_amdgcn_ds_swizzle(__float_as_int(v), 0x401F));
    }
}

#define TILES_PER_BLOCK 4
#define NTILE 1875                   // 32-e tiles per (b,which,chalf) combo
#define BLK4  ((NTILE + TILES_PER_BLOCK - 1) / TILES_PER_BLOCK)   // 469

// ---------------------------------------------------------------------------
// Kernel 0: prep = fuse-weight fold (blocks 0..59) + cst (block 60)
//                + transpose/quantize (blocks 61..).
// R6 transpose change (R1 structure retained, R5's LDS layout reverted):
// each block processes FOUR consecutive 32e x 64c tiles:
//   - all 8 loads/thread issued up-front -> 4x bytes in flight per wave
//   - per-row read span 512 B contiguous (4 adjacent 128 B chunks)
//   - ONE barrier per block instead of one per tile (turnaround amortized)
// LDS 33.3 KB -> 4 blocks/CU. Attacks the latency/turnaround bound
// (R1 prep: VALUBusy 9%, BW 2.5 TB/s, occupancy 56% -- nothing saturated).
// ---------------------------------------------------------------------------
__global__ __launch_bounds__(256) void prep_kernel(
    const float* __restrict__ x0, const float* __restrict__ x1,
    const float* __restrict__ Wa_local, const float* __restrict__ ba_local,
    const float* __restrict__ Wb_local, const float* __restrict__ bb_local,
    const float* __restrict__ Wa_tri,  const float* __restrict__ ba_tri,
    const float* __restrict__ Wb_tri,  const float* __restrict__ bb_tri,
    const float* __restrict__ Wa_fuse, const float* __restrict__ ba_fuse,
    const float* __restrict__ Wb_fuse, const float* __restrict__ bb_fuse,
    ushort_* __restrict__ xt, float* __restrict__ Vw, float* __restrict__ cst)
{
    __shared__ float tile[TILES_PER_BLOCK][32][65];   // 33.3 KB
    const int lane = threadIdx.x & 63;
    const int wv   = threadIdx.x >> 6;

    if (blockIdx.x < 60) {
        // ---- Vw: fold 256->3 fuse conv into tri (+local at s==0) weights ----
        float* smemf = &tile[0][0][0];
        const int pj    = blockIdx.x / 10;   // 0..5  (p,j)
        const int chunk = blockIdx.x % 10;   // 0..9
        const int p = pj / 3, j = pj % 3;
        const int f = chunk * 64 + lane;     // flat c*5+s
        const float* Wf = p ? Wb_fuse : Wa_fuse;   // [3][256]
        const float* Wt = p ? Wb_tri  : Wa_tri;    // [128][128][5] flat o*640+f
        const float* Wl = p ? Wb_local : Wa_local; // [128][128]
        const int o0 = wv * 32;              // each wave owns 32 of 128 o's
        float a0 = 0.f, a1 = 0.f, a2 = 0.f, a3 = 0.f;
        for (int o = o0; o < o0 + 32; o += 4) {
            a0 += Wf[j * 256 + 128 + o]     * Wt[(o)     * 640 + f];
            a1 += Wf[j * 256 + 129 + o]     * Wt[(o + 1) * 640 + f];
            a2 += Wf[j * 256 + 130 + o]     * Wt[(o + 2) * 640 + f];
            a3 += Wf[j * 256 + 131 + o]     * Wt[(o + 3) * 640 + f];
        }
        float acc = (a0 + a1) + (a2 + a3);
        const int s = f % 5, c = f / 5;
        if (s == 0) {   // absorb local conv into s=0 slot
            float b0 = 0.f, b1 = 0.f, b2 = 0.f, b3 = 0.f;
            for (int o = o0; o < o0 + 32; o += 4) {
                b0 += Wf[j * 256 + o]     * Wl[(o)     * C_ + c];
                b1 += Wf[j * 256 + o + 1] * Wl[(o + 1) * C_ + c];
                b2 += Wf[j * 256 + o + 2] * Wl[(o + 2) * C_ + c];
                b3 += Wf[j * 256 + o + 3] * Wl[(o + 3) * C_ + c];
            }
            acc += (b0 + b1) + (b2 + b3);
        }
        smemf[wv * 64 + lane] = acc;
        __syncthreads();
        if (wv == 0) {
            float tot = smemf[lane] + smemf[64 + lane] + smemf[128 + lane] + smemf[192 + lane];
            Vw[(pj * 5 + s) * C_ + c] = tot;
        }
    } else if (blockIdx.x == 60) {
        // ---- cst: one wave per output j, lanes parallel over o ----
        const int j = wv;
        if (j < 3) {
            float acc;
            {
                const int l = lane;
                acc = Wa_fuse[j * 256 + l]       * ba_local[l]
                    + Wa_fuse[j * 256 + 128 + l] * ba_tri[l]
                    + Wb_fuse[j * 256 + l]       * bb_local[l]
                    + Wb_fuse[j * 256 + 128 + l] * bb_tri[l];
            }
            {
                const int l = lane + 64;
                acc += Wa_fuse[j * 256 + l]       * ba_local[l]
                     + Wa_fuse[j * 256 + 128 + l] * ba_tri[l]
                     + Wb_fuse[j * 256 + l]       * bb_local[l]
                     + Wb_fuse[j * 256 + 128 + l] * bb_tri[l];
            }
            acc = swz_add(acc, 1); acc = swz_add(acc, 2); acc = swz_add(acc, 4);
            acc = swz_add(acc, 8); acc = swz_add(acc, 16);
            acc += __shfl_xor(acc, 32, 64);
            if (lane == 0) cst[j] = acc + ba_fuse[j] + bb_fuse[j];
        }
    } else {
        // ---- transpose + quantize: [B,C,E] f32 -> interleaved [b][e][2][C] bf16
        const int tb    = blockIdx.x - 61;   // 0 .. 8*BLK4-1
        const int combo = tb / BLK4;         // 0..7
        const int blk4  = tb % BLK4;         // 0..468
        const int by    = combo & 1;         // channel half (64 ch)
        const int bz    = combo >> 1;        // 0..3
        const int which = bz >> 1;           // 0 -> x0, 1 -> x1
        const int b     = bz & 1;
        const float* src = (which ? x1 : x0) + (size_t)b * C_ * E_;
        const int c0 = by * 64;
        const int t  = threadIdx.x;
        const int nt = min(TILES_PER_BLOCK, NTILE - blk4 * TILES_PER_BLOCK);

        const int c  = t >> 2;               // 0..63
        const int e8 = (t & 3) * 8;          // 0,8,16,24
        const float* rowp = src + (size_t)(c0 + c) * E_ + blk4 * (TILES_PER_BLOCK * 32) + e8;

        // issue all loads up-front (8 independent float4 per thread)
        float4 v0[TILES_PER_BLOCK], v1[TILES_PER_BLOCK];
#pragma unroll
        for (int k = 0; k < TILES_PER_BLOCK; ++k) {
            if (k < nt) {
                v0[k] = *(const float4*)(rowp + k * 32);
                v1[k] = *(const float4*)(rowp + k * 32 + 4);
            }
        }
#pragma unroll
        for (int k = 0; k < TILES_PER_BLOCK; ++k) {
            if (k < nt) {
                tile[k][e8 + 0][c] = v0[k].x; tile[k][e8 + 1][c] = v0[k].y;
                tile[k][e8 + 2][c] = v0[k].z; tile[k][e8 + 3][c] = v0[k].w;
                tile[k][e8 + 4][c] = v1[k].x; tile[k][e8 + 5][c] = v1[k].y;
                tile[k][e8 + 6][c] = v1[k].z; tile[k][e8 + 7][c] = v1[k].w;
            }
        }
        __syncthreads();
        {
            const int e  = t >> 3;           // 0..31
            const int c8 = (t & 7) * 8;      // 0..56
#pragma unroll
            for (int k = 0; k < TILES_PER_BLOCK; ++k) {
                if (k < nt) {
                    const float* r = &tile[k][e][c8];
                    uint32_ w0 = (uint32_)f2b(r[0]) | ((uint32_)f2b(r[1]) << 16);
                    uint32_ w1 = (uint32_)f2b(r[2]) | ((uint32_)f2b(r[3]) << 16);
                    uint32_ w2 = (uint32_)f2b(r[4]) | ((uint32_)f2b(r[5]) << 16);
                    uint32_ w3 = (uint32_)f2b(r[6]) | ((uint32_)f2b(r[7]) << 16);
                    uint4 w; w.x = w0; w.y = w1; w.z = w2; w.w = w3;
                    const int e0 = (blk4 * TILES_PER_BLOCK + k) * 32;
                    const size_t rec = (size_t)((b * E_ + e0 + e) * 2 + which);
                    *(uint4*)(xt + (rec << 7) + c0 + c8) = w;
                }
            }
        }
    }
}

// ---------------------------------------------------------------------------
// Kernel 1: fused gather + features + 3-channel projection (R4-proven form).
// One record (512 B) = ONE global_load_dwordx2 across the wave. Lane l owns
// 4 channels of tensor p=(l>>5). Mesh is at the random-line service-rate
// wall (~48us): pipelining (R1/R2), width (R4), working-set (R3), and
// self-stream removal (R5) all measured null or ~2us.
// ---------------------------------------------------------------------------
__global__ __launch_bounds__(256, 4) void mesh_fused_kernel(
    const uint2* __restrict__ xt2, const int* __restrict__ gemm,
    const float* __restrict__ Vw, const float* __restrict__ cst,
    float* __restrict__ out)
{
    const int lane = threadIdx.x & 63;
    const int wv   = threadIdx.x >> 6;
    const int gw   = blockIdx.x * 4 + wv;
    const int nw   = gridDim.x * 4;

    const int p  = lane >> 5;          // tensor this lane handles
    const int c4 = (lane & 31) * 4;    // first of 4 channels this lane handles
    v4f w[3][5];
#pragma unroll
    for (int j = 0; j < 3; ++j)
#pragma unroll
        for (int s = 0; s < 5; ++s)
            w[j][s] = *(const v4f*)(Vw + ((p * 3 + j) * 5 + s) * C_ + c4);

    const int  jj     = lane >> 4;                 // 0..3
    const bool is0    = (jj == 0), is1 = (jj == 1);
    const bool writer = ((lane & 15) == 0) && (jj < 3);
    const float cj    = is0 ? cst[0] : (is1 ? cst[1] : cst[2]);
    float* obase      = out + (size_t)(jj < 3 ? jj : 2) * E_;

    const int4* g4 = (const int4*)gemm;
    const int npair = (B_ * E_) / 2;               // gw < npair (nw <= 8192)

    int4 giA = g4[2 * gw], giB = g4[2 * gw + 1];   // index prefetch

    for (int pair = gw; pair < npair; pair += nw) {
        const int nxt = pair + nw;
        const int4 gA = giA, gB = giB;
        if (nxt < npair) { giA = g4[2 * nxt]; giB = g4[2 * nxt + 1]; }

        const int e0 = 2 * pair;                   // global edge id of edge A
        const uint32_ badd = (e0 >= E_) ? (uint32_)E_ : 0u;

        // 10 wave-wide 512 B gathers (uint2 per lane), all independent
        const uint2 SA = xt2[(((uint32_)e0)     << 6) + lane];
        const uint2 SB = xt2[(((uint32_)e0 + 1) << 6) + lane];
        const uint2 A1 = xt2[((badd + (uint32_)gA.x) << 6) + lane];
        const uint2 A2 = xt2[((badd + (uint32_)gA.y) << 6) + lane];
        const uint2 A3 = xt2[((badd + (uint32_)gA.z) << 6) + lane];
        const uint2 A4 = xt2[((badd + (uint32_)gA.w) << 6) + lane];
        const uint2 B1 = xt2[((badd + (uint32_)gB.x) << 6) + lane];
        const uint2 B2 = xt2[((badd + (uint32_)gB.y) << 6) + lane];
        const uint2 B3 = xt2[((badd + (uint32_)gB.z) << 6) + lane];
        const uint2 B4 = xt2[((badd + (uint32_)gB.w) << 6) + lane];

        // ---- edge A ----
        float rA0, rA1, rA2;
        {
            v4f a0 = bp4(SA);
            v4f a1 = bp4(A1), a2 = bp4(A2), a3 = bp4(A3), a4 = bp4(A4);
            v4f s1 = a1 + a3, s2 = a2 + a4;
            v4f d1 = vabs4(a1 - a3), d2 = vabs4(a2 - a4);
            v4f t0 = w[0][0] * a0, t1 = w[1][0] * a0, t2 = w[2][0] * a0;
            t0 += w[0][1] * s1; t1 += w[1][1] * s1; t2 += w[2][1] * s1;
            t0 += w[0][2] * s2; t1 += w[1][2] * s2; t2 += w[2][2] * s2;
            t0 += w[0][3] * d1; t1 += w[1][3] * d1; t2 += w[2][3] * d1;
            t0 += w[0][4] * d2; t1 += w[1][4] * d2; t2 += w[2][4] * d2;
            rA0 = (t0.x + t0.y) + (t0.z + t0.w);
            rA1 = (t1.x + t1.y) + (t1.z + t1.w);
            rA2 = (t2.x + t2.y) + (t2.z + t2.w);
        }
        // ---- edge B ----
        float rB0, rB1, rB2;
        {
            v4f a0 = bp4(SB);
            v4f a1 = bp4(B1), a2 = bp4(B2), a3 = bp4(B3), a4 = bp4(B4);
            v4f s1 = a1 + a3, s2 = a2 + a4;
            v4f d1 = vabs4(a1 - a3), d2 = vabs4(a2 - a4);
            v4f t0 = w[0][0] * a0, t1 = w[1][0] * a0, t2 = w[2][0] * a0;
            t0 += w[0][1] * s1; t1 += w[1][1] * s1; t2 += w[2][1] * s1;
            t0 += w[0][2] * s2; t1 += w[1][2] * s2; t2 += w[2][2] * s2;
            t0 += w[0][3] * d1; t1 += w[1][3] * d1; t2 += w[2][3] * d1;
            t0 += w[0][4] * d2; t1 += w[1][4] * d2; t2 += w[2][4] * d2;
            rB0 = (t0.x + t0.y) + (t0.z + t0.w);
            rB1 = (t1.x + t1.y) + (t1.z + t1.w);
            rB2 = (t2.x + t2.y) + (t2.z + t2.w);
        }

        // full 64-lane reduce (both tensors + all channels), A/B interleaved
        rA0 = swz_add(rA0, 16); rB0 = swz_add(rB0, 16);
        rA1 = swz_add(rA1, 16); rB1 = swz_add(rB1, 16);
        rA2 = swz_add(rA2, 16); rB2 = swz_add(rB2, 16);
        rA0 += __shfl_xor(rA0, 32, 64); rB0 += __shfl_xor(rB0, 32, 64);
        rA1 += __shfl_xor(rA1, 32, 64); rB1 += __shfl_xor(rB1, 32, 64);
        rA2 += __shfl_xor(rA2, 32, 64); rB2 += __shfl_xor(rB2, 32, 64);

        float vA = is0 ? rA0 : (is1 ? rA1 : rA2);
        float vB = is0 ? rB0 : (is1 ? rB1 : rB2);
        vA = swz_add(vA, 1); vB = swz_add(vB, 1);
        vA = swz_add(vA, 2); vB = swz_add(vB, 2);
        vA = swz_add(vA, 4); vB = swz_add(vB, 4);
        vA = swz_add(vA, 8); vB = swz_add(vB, 8);

        if (writer) {
            const int bb = (e0 >= E_) ? 1 : 0;
            const int ee = e0 - (bb ? E_ : 0);
            float2 st; st.x = vA + cj; st.y = vB + cj;
            *(float2*)(obase + (bb ? 3 * E_ : 0) + ee) = st;   // ee even -> aligned
        }
    }
}

extern "C" void kernel_launch(void* const* d_in, const int* in_sizes, int n_in,
                              void* d_out, int out_size, void* d_ws, size_t ws_size,
                              hipStream_t stream) {
    const float* x0       = (const float*)d_in[0];
    const float* x1       = (const float*)d_in[1];
    const int*   gemm     = (const int*)d_in[2];
    const float* Wa_local = (const float*)d_in[3];
    const float* ba_local = (const float*)d_in[4];
    const float* Wb_local = (const float*)d_in[5];
    const float* bb_local = (const float*)d_in[6];
    const float* Wa_tri   = (const float*)d_in[7];
    const float* ba_tri   = (const float*)d_in[8];
    const float* Wb_tri   = (const float*)d_in[9];
    const float* bb_tri   = (const float*)d_in[10];
    const float* Wa_fuse  = (const float*)d_in[11];
    const float* ba_fuse  = (const float*)d_in[12];
    const float* Wb_fuse  = (const float*)d_in[13];
    const float* bb_fuse  = (const float*)d_in[14];
    float* out = (float*)d_out;

    ushort_* xt  = (ushort_*)d_ws;                       // [B][E][2][C] bf16
    float*   Vw  = (float*)(xt + (size_t)B_ * E_ * 2 * C_);
    float*   cst = Vw + 2 * 3 * 5 * C_;

    hipLaunchKernelGGL(prep_kernel, dim3(61 + 8 * BLK4), dim3(256), 0, stream,
                       x0, x1,
                       Wa_local, ba_local, Wb_local, bb_local,
                       Wa_tri, ba_tri, Wb_tri, bb_tri,
                       Wa_fuse, ba_fuse, Wb_fuse, bb_fuse, xt, Vw, cst);

    hipLaunchKernelGGL(mesh_fused_kernel, dim3(2048), dim3(256), 0, stream,
                       (const uint2*)xt, gemm, Vw, cst, out);
}